// Round 3
// baseline (626.144 us; speedup 1.0000x reference)
//
#include <hip/hip_runtime.h>
#include <cstdint>

#define ROW_N 8192
#define TPB   1024   // 16 waves; 2 blocks/CU at <=64 VGPR -> 100% occupancy
#define NW    16
#define EPT   8      // elements per thread
#define CAP   1024

// Order-preserving float->uint32 transform: unsigned compare == float compare.
__device__ __forceinline__ unsigned int fkey(float p) {
  unsigned int b = __float_as_uint(p);
  return (b & 0x80000000u) ? ~b : (b | 0x80000000u);
}
__device__ __forceinline__ float fkey_inv(unsigned int t) {
  unsigned int b = (t & 0x80000000u) ? (t & 0x7fffffffu) : ~t;
  return __uint_as_float(b);
}

// Screening key = perturbed * log2e via 2 native v_log_f32 (|err| < ~0.02
// log2-units for w >= 1e-5; margin is 0.25). For w < 1e-5 (u ~ 1: HW log2's
// abs error near 1.0 is a large RELATIVE error on w) emit a LOWER BOUND key
// (precise p >= lg + 11.5129 since -ln(w') >= -ln(1e-5)) and flag: flagged
// elements are force-included as candidates, so the screen stays a superset
// of the true top-32 even if a row is full of saturated u's.
__device__ __forceinline__ unsigned int akey(float lg, float uu, bool& sat) {
  float l2u = __log2f(uu + 1e-8f);
  float w   = fmaf(l2u, -0.6931471805599453f, 1e-8f);
  sat = (w < 1e-5f);
  float p2  = fmaf(lg, 1.4426950408889634f, -__log2f(w));
  float lb  = (lg + 11.512925f) * 1.4426950408889634f;
  return fkey(sat ? lb : p2);
}

__device__ __forceinline__ uint64_t shfl_xor_u64(uint64_t v, int m) {
  unsigned int lo = (unsigned int)v, hi = (unsigned int)(v >> 32);
  lo = __shfl_xor(lo, m, 64);
  hi = __shfl_xor(hi, m, 64);
  return ((uint64_t)hi << 32) | lo;
}
__device__ __forceinline__ uint64_t wave_max_u64(uint64_t v) {
#pragma unroll
  for (int s = 32; s >= 1; s >>= 1) {
    uint64_t o = shfl_xor_u64(v, s);
    v = (o > v) ? o : v;
  }
  return v;
}
__device__ __forceinline__ unsigned int wave_max_u32(unsigned int v) {
#pragma unroll
  for (int s = 32; s >= 1; s >>= 1) {
    unsigned int o = __shfl_xor(v, s, 64);
    v = max(v, o);
  }
  return v;
}

__global__ __launch_bounds__(TPB, 8) void gumbel_topk_kernel(
    const float* __restrict__ logits, const float* __restrict__ u,
    float* __restrict__ out) {
  const int row  = blockIdx.x;
  const int tid  = threadIdx.x;
  const int lane = tid & 63;
  const int wave = tid >> 6;

  __shared__ unsigned int s_cnt;
  __shared__ unsigned int s_tw[NW];
  __shared__ unsigned int s_idx[CAP];    // candidate element indices
  __shared__ uint64_t     s_comp[CAP];   // precise composite keys
  __shared__ float        s_lg[CAP];     // candidate original logits
  __shared__ float        s_red[NW];     // wave maxes
  __shared__ float        s_red2[NW];    // wave sums

  if (tid == 0) s_cnt = 0;

  const float4* L4 = reinterpret_cast<const float4*>(logits) + (size_t)row * (ROW_N / 4);
  const float4* U4 = reinterpret_cast<const float4*>(u)      + (size_t)row * (ROW_N / 4);
  float4*       O4 = reinterpret_cast<float4*>(out)          + (size_t)row * (ROW_N / 4);

  // ---- Phase A: approx screening keys, 8/thread (2 v_log + ~6 VALU each)
  unsigned int k[EPT];
  unsigned int satm = 0;
  unsigned int M = 0;
#pragma unroll
  for (int j = 0; j < EPT / 4; ++j) {
    float4 lv = L4[j * TPB + tid];
    float4 uv = U4[j * TPB + tid];
    bool s0, s1, s2, s3;
    k[j * 4 + 0] = akey(lv.x, uv.x, s0);
    k[j * 4 + 1] = akey(lv.y, uv.y, s1);
    k[j * 4 + 2] = akey(lv.z, uv.z, s2);
    k[j * 4 + 3] = akey(lv.w, uv.w, s3);
    satm |= ((s0 ? 1u : 0u) | (s1 ? 2u : 0u) | (s2 ? 4u : 0u) | (s3 ? 8u : 0u)) << (j * 4);
    M = max(M, max(max(k[j * 4 + 0], k[j * 4 + 1]), max(k[j * 4 + 2], k[j * 4 + 3])));
  }

  // ---- Zero-fill output row early (barriers below drain vmcnt before scatter).
  {
    float4 z = make_float4(0.f, 0.f, 0.f, 0.f);
#pragma unroll
    for (int j = 0; j < EPT / 4; ++j) O4[j * TPB + tid] = z;
  }

  // ---- Phase B: t = min over 16 waves of (2nd-largest of 64 thread-maxes).
  // Each wave then holds >=2 elements >= t -> >=32 block-wide -> t <= true
  // 32nd-largest key. ~14 shuffle ops per wave, no LDS counting.
  unsigned int wm1 = wave_max_u32(M);
  unsigned int Mx  = (M == wm1) ? 0u : M;   // ties: 2nd == 1st, bound still valid
  unsigned int wm2 = wave_max_u32(Mx);
  if (lane == 0) s_tw[wave] = wm2;
  __syncthreads();  // B1 (also orders s_cnt=0 before Phase C atomics)
  unsigned int t = 0xFFFFFFFFu;
#pragma unroll
  for (int i = 0; i < NW; ++i) t = min(t, s_tw[i]);
  unsigned int tm = (t == 0u) ? 0u : fkey(fkey_inv(t) - 0.25f);  // margin 0.25

  // ---- Phase C: collect candidates (approx key >= tm, or hazard-flagged).
#pragma unroll
  for (int i = 0; i < EPT; ++i) {
    if (k[i] >= tm || ((satm >> i) & 1u)) {
      unsigned int slot = atomicAdd(&s_cnt, 1u);
      if (slot < CAP)
        s_idx[slot] = (unsigned int)((i >> 2) * (TPB * 4) + tid * 4 + (i & 3));
    }
  }
  __syncthreads();  // B2
  unsigned int C = s_cnt;

  // ---- Fallback (adversarial ties only; never for iid data): per-wave top-32
  // by approx composite -> union of 512 indices.
  if (C > CAP) {
#pragma unroll 1
    for (int it = 0; it < 32; ++it) {
      uint64_t lm = 0;
#pragma unroll
      for (int i = 0; i < EPT; ++i) {
        unsigned int idx = (unsigned int)((i >> 2) * (TPB * 4) + tid * 4 + (i & 3));
        uint64_t comp = ((uint64_t)k[i] << 13) | (uint64_t)(8191u - idx);
        if (k[i] != 0u && comp > lm) lm = comp;
      }
      uint64_t wm = wave_max_u64(lm);
      if (lm == wm && lm != 0) {
#pragma unroll
        for (int i = 0; i < EPT; ++i) {
          unsigned int idx = (unsigned int)((i >> 2) * (TPB * 4) + tid * 4 + (i & 3));
          uint64_t comp = ((uint64_t)k[i] << 13) | (uint64_t)(8191u - idx);
          if (comp == wm) k[i] = 0u;
        }
      }
      if (lane == 0) s_idx[wave * 32 + it] = 8191u - (unsigned int)(wm & 8191u);
    }
    __syncthreads();
    C = NW * 32;  // 512
  }

  // ---- Phase D1: precise recompute (ocml logf, ONE textual copy) for the
  // ~120 candidates. Composite (key<<13)|(8191-idx): distinct, bigger=better,
  // ties -> smaller index (jax.lax.top_k rule).
  const float* Lrow = logits + (size_t)row * ROW_N;
  const float* Urow = u      + (size_t)row * ROW_N;
  float lg = 0.f;
  unsigned int idx = 0;
  if (tid < (int)C) {
    idx = s_idx[tid];
    lg  = Lrow[idx];
    float uu = Urow[idx];
    float p  = lg - logf(-logf(uu + 1e-8f) + 1e-8f);
    s_comp[tid] = ((uint64_t)fkey(p) << 13) | (uint64_t)(8191u - idx);
    s_lg[tid]   = lg;
  }
  __syncthreads();  // B3

  // ---- Phase D2: exact selection by rank-counting (broadcast LDS reads;
  // composites distinct => exactly 32 ranks < 32).
  bool sel = false;
  if (tid < (int)C) {
    uint64_t mine = s_comp[tid];
    unsigned int cnt = 0;
#pragma unroll 1
    for (unsigned int i = 0; i < C; ++i) cnt += (s_comp[i] > mine) ? 1u : 0u;
    sel = (cnt < 32);
  }

  // ---- Softmax over the ORIGINAL logits of the 32 selected.
  float mv = sel ? lg : -3.4e38f;
#pragma unroll
  for (int s = 32; s >= 1; s >>= 1) mv = fmaxf(mv, __shfl_xor(mv, s, 64));
  if (lane == 0) s_red[wave] = mv;
  __syncthreads();  // B4
  float m = -3.4e38f;
#pragma unroll
  for (int i = 0; i < NW; ++i) m = fmaxf(m, s_red[i]);

  float e = sel ? __expf(lg - m) * 0.f + expf(lg - m) : 0.f;  // keep ocml expf
  float sum = e;
#pragma unroll
  for (int s = 32; s >= 1; s >>= 1) sum += __shfl_xor(sum, s, 64);
  if (lane == 0) s_red2[wave] = sum;
  __syncthreads();  // B5 (drains zero-fill stores before the scatter)
  sum = 0.f;
#pragma unroll
  for (int i = 0; i < NW; ++i) sum += s_red2[i];

  if (sel) out[(size_t)row * ROW_N + idx] = e / sum;
}

extern "C" void kernel_launch(void* const* d_in, const int* in_sizes, int n_in,
                              void* d_out, int out_size, void* d_ws, size_t ws_size,
                              hipStream_t stream) {
  const float* logits = (const float*)d_in[0];
  const float* u      = (const float*)d_in[1];
  float*       out    = (float*)d_out;
  int rows = in_sizes[0] / ROW_N;   // 8192
  gumbel_topk_kernel<<<dim3(rows), dim3(TPB), 0, stream>>>(logits, u, out);
}